// Round 3
// baseline (326.322 us; speedup 1.0000x reference)
//
#include <hip/hip_runtime.h>

// Problem constants (from reference): SEQ=1024, B=32, H=1024
#define SEQ 1024
#define NCH 32768   // B*H independent channels
#define UNR 32      // timesteps per register buffer (64 loads in flight ~= vmcnt cap)
#define NC  (SEQ / UNR)  // 32 chunks, 2 per outer iteration

// One thread per channel, [t][channel] layout -> coalesced at every step.
// Wave count is pinned at 512 (serial recurrence), i.e. 0.5 waves/SIMD, so
// the only latency-hiding is per-wave MLP: double-buffered UNR=32 chunks
// keep 64 loads (16 KB/wave) in flight -- at the vmcnt=63 hardware cap.
// Critical path: precompute p=f*x, q=1-f off-chain, then h=fma(q,h,p) is a
// single dependent op (~4.6 cyc) per timestep.
// __launch_bounds__(64,1): 1 wave/EU minimum -> allocator may use up to
// 512 VGPRs; ~192 data regs live, must not spill.
__global__ __launch_bounds__(64, 1) void fm_scan(const float* __restrict__ f,
                                                 const float* __restrict__ x,
                                                 const float* __restrict__ h0,
                                                 float* __restrict__ out) {
    const int idx = blockIdx.x * 64 + threadIdx.x;  // channel id
    const float* fp = f + idx;
    const float* xp = x + idx;
    float* op = out + idx;

    float h = h0[idx];

    float fTA[UNR], xTA[UNR], fTB[UNR], xTB[UNR];
    float p[UNR], q[UNR];

    // Prologue: load chunk 0 into TA.
#pragma unroll
    for (int j = 0; j < UNR; ++j) {
        fTA[j] = fp[(size_t)j * NCH];
        xTA[j] = xp[(size_t)j * NCH];
    }

    for (int c = 0; c < NC; c += 2) {
        const size_t b0 = (size_t)c * UNR * NCH;  // element offset of chunk c

        // Issue chunk c+1 loads into TB (in flight during A's compute).
#pragma unroll
        for (int j = 0; j < UNR; ++j) {
            fTB[j] = fp[b0 + (size_t)(UNR + j) * NCH];
            xTB[j] = xp[b0 + (size_t)(UNR + j) * NCH];
        }

        // Convert TA -> p,q (independent ops; TA loads long since landed).
#pragma unroll
        for (int j = 0; j < UNR; ++j) {
            p[j] = fTA[j] * xTA[j];
            q[j] = 1.0f - fTA[j];
        }
        // Chunk c: one dependent FMA per step. out is never re-read -> nt
        // stores keep the LLC-resident f/x from being evicted.
#pragma unroll
        for (int j = 0; j < UNR; ++j) {
            h = fmaf(q[j], h, p[j]);
            __builtin_nontemporal_store(h, &op[b0 + (size_t)j * NCH]);
        }

        // Issue chunk c+2 loads into TA (in flight during B's compute).
        if (c + 2 < NC) {
#pragma unroll
            for (int j = 0; j < UNR; ++j) {
                fTA[j] = fp[b0 + (size_t)(2 * UNR + j) * NCH];
                xTA[j] = xp[b0 + (size_t)(2 * UNR + j) * NCH];
            }
        }

        // Convert TB -> p,q.
#pragma unroll
        for (int j = 0; j < UNR; ++j) {
            p[j] = fTB[j] * xTB[j];
            q[j] = 1.0f - fTB[j];
        }
        // Chunk c+1.
#pragma unroll
        for (int j = 0; j < UNR; ++j) {
            h = fmaf(q[j], h, p[j]);
            __builtin_nontemporal_store(h, &op[b0 + (size_t)(UNR + j) * NCH]);
        }
    }
}

extern "C" void kernel_launch(void* const* d_in, const int* in_sizes, int n_in,
                              void* d_out, int out_size, void* d_ws, size_t ws_size,
                              hipStream_t stream) {
    const float* f  = (const float*)d_in[0];
    const float* x  = (const float*)d_in[1];
    const float* h0 = (const float*)d_in[2];
    float* out = (float*)d_out;

    // 512 blocks of 64 threads: 2 blocks/CU over all 256 CUs.
    fm_scan<<<dim3(NCH / 64), dim3(64), 0, stream>>>(f, x, h0, out);
}